// Round 1
// baseline (1330.391 us; speedup 1.0000x reference)
//
#include <hip/hip_runtime.h>
#include <hip/hip_bf16.h>
#include <stdint.h>

// ---------------------------------------------------------------------------
// MultiHeadAttention fwd. B=4 H=8 S=2048 D=768 depth=96.
// Outputs: out [4,2048,768] fp32, attn [4,8,2048,2048] fp32 (concat in d_out).
// R3:
//  - attn_kernel: 2-way kt-split per q-tile (2 q-groups x 2 kt-halves per
//    block, grid 2048 blocks -> 8 blocks/CU, 32 waves/CU). Attacks the
//    latency-bound 40%-occupancy profile (MfmaUtil 6.7 / VALU 11 / HBM 19%).
//  - proj/oproj: m97-structure staging via __builtin_amdgcn_global_load_lds
//    width=16 (no VALU in staging); inputs pre-converted to bf16 (xcvt).
// Fragment layouts: A: m=lane&15,k=quad*8+j  B(=Bt[n][k]): n=lane&15,k=quad*8+j
//                   C/D: col=lane&15, row=quad*4+reg
// ---------------------------------------------------------------------------

#define SEQ 2048
#define DM 768
#define NB 4
#define NH 8
#define DEP 96
#define MROWS 8192  // NB*SEQ

typedef __bf16 bf16x8 __attribute__((ext_vector_type(8)));
typedef float f32x4 __attribute__((ext_vector_type(4)));

__device__ inline unsigned short f2b(float f) {
    return __builtin_bit_cast(unsigned short, (__bf16)f);
}
__device__ inline bf16x8 ld_frag(const unsigned short* p) {
    return __builtin_bit_cast(bf16x8, *(const uint4*)p);
}
__device__ inline void gload_lds16(const unsigned short* g, unsigned short* l) {
    __builtin_amdgcn_global_load_lds(
        (const __attribute__((address_space(1))) unsigned int*)g,
        (__attribute__((address_space(3))) unsigned int*)l, 16, 0, 0);
}

// ---- 1. weight transpose: W fp32 [768][768] -> Wt bf16 [768][768], Wt[n][k]=W[k][n]
__global__ __launch_bounds__(256) void wt_kernel(
    const float* __restrict__ w0, const float* __restrict__ w1,
    const float* __restrict__ w2, const float* __restrict__ w3,
    unsigned short* __restrict__ wt)
{
    __shared__ float tile[32][33];
    int mat = blockIdx.z;
    const float* w = mat == 0 ? w0 : mat == 1 ? w1 : mat == 2 ? w2 : w3;
    unsigned short* dst = wt + (size_t)mat * DM * DM;
    int k0 = blockIdx.x * 32, n0 = blockIdx.y * 32;
    int tx = threadIdx.x & 31, ty = threadIdx.x >> 5;
#pragma unroll
    for (int i = 0; i < 4; i++)
        tile[ty + i * 8][tx] = w[(size_t)(k0 + ty + i * 8) * DM + n0 + tx];
    __syncthreads();
#pragma unroll
    for (int i = 0; i < 4; i++)
        dst[(size_t)(n0 + ty + i * 8) * DM + k0 + tx] = f2b(tile[tx][ty + i * 8]);
}

// ---- 1b. input convert: q_in/k_in/v_in fp32 [8192][768] -> bf16 (same layout)
__global__ __launch_bounds__(256) void xcvt_kernel(
    const float* __restrict__ q, const float* __restrict__ k, const float* __restrict__ v,
    unsigned short* __restrict__ xb)
{
    int z = blockIdx.z;
    const float* src = z == 0 ? q : z == 1 ? k : v;
    unsigned short* dst = xb + (size_t)z * MROWS * DM;
    size_t i = ((size_t)blockIdx.x * 256 + threadIdx.x) * 8;
    float4 f0 = *(const float4*)(src + i);
    float4 f1 = *(const float4*)(src + i + 4);
    bf16x8 p;
    p[0] = (__bf16)f0.x; p[1] = (__bf16)f0.y; p[2] = (__bf16)f0.z; p[3] = (__bf16)f0.w;
    p[4] = (__bf16)f1.x; p[5] = (__bf16)f1.y; p[6] = (__bf16)f1.z; p[7] = (__bf16)f1.w;
    *(uint4*)(dst + i) = __builtin_bit_cast(uint4, p);
}

// ---- 2. QKV projection GEMM (m97 structure: global_load_lds staging, 128x128x32)
__global__ __launch_bounds__(256) void proj_kernel(
    const unsigned short* __restrict__ xb, const unsigned short* __restrict__ wt,
    const float* __restrict__ bq, const float* __restrict__ bk, const float* __restrict__ bv,
    unsigned short* __restrict__ qb, unsigned short* __restrict__ kb, unsigned short* __restrict__ vb)
{
    __shared__ unsigned short As[128 * 32];
    __shared__ unsigned short Bs[128 * 32];

    int z = blockIdx.z;
    const unsigned short* x = xb + (size_t)z * MROWS * DM;
    const unsigned short* W = wt + (size_t)z * DM * DM;
    const float* bias = z == 0 ? bq : z == 1 ? bk : bv;
    unsigned short* out = z == 0 ? qb : z == 1 ? kb : vb;

    int tid = threadIdx.x;
    int lane = tid & 63, wv_ = tid >> 6;
    int col = lane & 15, quad = lane >> 4;
    int m0 = blockIdx.x * 128, n0 = blockIdx.y * 128;
    int mi = (wv_ & 1) * 64, ni = (wv_ >> 1) * 64;
    int sr = tid >> 2, so = (tid & 3) * 8;  // staging row 0..63, k-offset

    f32x4 acc[4][4] = {};
    for (int kk = 0; kk < DM; kk += 32) {
        __syncthreads();
        gload_lds16(x + (size_t)(m0 + sr) * DM + kk + so,      &As[tid * 8]);
        gload_lds16(x + (size_t)(m0 + 64 + sr) * DM + kk + so, &As[2048 + tid * 8]);
        gload_lds16(W + (size_t)(n0 + sr) * DM + kk + so,      &Bs[tid * 8]);
        gload_lds16(W + (size_t)(n0 + 64 + sr) * DM + kk + so, &Bs[2048 + tid * 8]);
        __syncthreads();
        bf16x8 af[4], bfr[4];
#pragma unroll
        for (int mt = 0; mt < 4; mt++)
            af[mt] = ld_frag(&As[(mi + mt * 16 + col) * 32 + quad * 8]);
#pragma unroll
        for (int nt = 0; nt < 4; nt++)
            bfr[nt] = ld_frag(&Bs[(ni + nt * 16 + col) * 32 + quad * 8]);
#pragma unroll
        for (int mt = 0; mt < 4; mt++)
#pragma unroll
            for (int nt = 0; nt < 4; nt++)
                acc[mt][nt] = __builtin_amdgcn_mfma_f32_16x16x32_bf16(af[mt], bfr[nt], acc[mt][nt], 0, 0, 0);
    }
#pragma unroll
    for (int mt = 0; mt < 4; mt++) {
        int grow_base = m0 + mi + mt * 16 + quad * 4;
#pragma unroll
        for (int nt = 0; nt < 4; nt++) {
            int gcol = n0 + ni + nt * 16 + col;
            float bv_ = bias[gcol];
            int h = gcol / DEP, d = gcol % DEP;
#pragma unroll
            for (int r = 0; r < 4; r++) {
                int grow = grow_base + r;
                int b = grow >> 11, s = grow & 2047;
                out[((size_t)((b * NH + h) * SEQ + s)) * DEP + d] = f2b(acc[mt][nt][r] + bv_);
            }
        }
    }
}

// ---- 3. V transpose: [bh][S][96] -> [bh][96][S] (bf16)
__global__ __launch_bounds__(256) void vt_kernel(
    const unsigned short* __restrict__ vb, unsigned short* __restrict__ vt)
{
    __shared__ unsigned short tile[32][33];
    int bh = blockIdx.z;
    int s0 = blockIdx.x * 32, d0 = blockIdx.y * 32;
    int tx = threadIdx.x & 31, ty = threadIdx.x >> 5;
    const unsigned short* src = vb + (size_t)bh * SEQ * DEP;
    unsigned short* dst = vt + (size_t)bh * DEP * SEQ;
#pragma unroll
    for (int i = 0; i < 4; i++)
        tile[ty + i * 8][tx] = src[(size_t)(s0 + ty + i * 8) * DEP + d0 + tx];
    __syncthreads();
#pragma unroll
    for (int i = 0; i < 4; i++)
        dst[(size_t)(d0 + ty + i * 8) * SEQ + s0 + tx] = tile[tx][ty + i * 8];
}

// ---- 4. attention: barrier-light, direct-global K/V fragment loads.
// R3: 2-way kt-split. Block = 4 waves = 2 q-groups(16 rows) x 2 kt-halves.
// Grid (SEQ/32, BH) = 2048 blocks -> 8 blocks/CU -> 32 waves/CU (was 16).
// Denominator and O-partials combined through small LDS buffers.
__global__ __launch_bounds__(256, 8) void attn_kernel(
    const unsigned short* __restrict__ qb, const unsigned short* __restrict__ kb,
    const unsigned short* __restrict__ vt, const float* __restrict__ mask,
    float* __restrict__ attn_out, unsigned short* __restrict__ ctx)
{
    __shared__ float mask_s[SEQ];                 // 8 KB, pre-multiplied by -1e9
    __shared__ unsigned short p_lds[4][16 * 72];  // per-wave P transpose, rows padded 64->72
    __shared__ float lsum_x[2][2][16];            // [qg][kh][row] partial denominators
    __shared__ f32x4 o_xchg[2][64];               // [qg][lane] O-partial exchange

    int tid = threadIdx.x;
    int w = tid >> 6, lane = tid & 63, col = lane & 15, quad = lane >> 4;
    int qg = w & 1, kh = w >> 1;
    int bh = blockIdx.y;
    int b = bh >> 3, h = bh & 7;
    int q0 = blockIdx.x * 32 + qg * 16;
    int kbeg = kh * (SEQ / 2), kend = kbeg + SEQ / 2;

    const unsigned short* Qp = qb + (size_t)bh * SEQ * DEP;
    const unsigned short* Kp = kb + (size_t)bh * SEQ * DEP;
    const unsigned short* Vp = vt + (size_t)bh * DEP * SEQ;
    float* attn = attn_out + (size_t)bh * SEQ * SEQ;

    for (int i = tid; i < SEQ; i += 256)
        mask_s[i] = mask[b * SEQ + i] * (-1e9f);
    __syncthreads();

    bf16x8 aq[3];
#pragma unroll
    for (int ks = 0; ks < 3; ks++)
        aq[ks] = ld_frag(Qp + (size_t)(q0 + col) * DEP + ks * 32 + quad * 8);

    const float scale = 0.10206207261596575f;  // 1/sqrt(96)
    float lsum[4] = {0.f, 0.f, 0.f, 0.f};

    // ---- pass 1: partial denominators over this wave's kt-half
    for (int kt = kbeg; kt < kend; kt += 64) {
#pragma unroll
        for (int nt = 0; nt < 4; nt++) {
            const unsigned short* kr = Kp + (size_t)(kt + nt * 16 + col) * DEP;
            f32x4 c = {0.f, 0.f, 0.f, 0.f};
#pragma unroll
            for (int ks = 0; ks < 3; ks++)
                c = __builtin_amdgcn_mfma_f32_16x16x32_bf16(aq[ks], ld_frag(kr + ks * 32 + quad * 8), c, 0, 0, 0);
            float mv = mask_s[kt + nt * 16 + col];
#pragma unroll
            for (int r = 0; r < 4; r++)
                lsum[r] += __expf(c[r] * scale + mv);
        }
    }
#pragma unroll
    for (int r = 0; r < 4; r++) {
        float v = lsum[r];
        v += __shfl_xor(v, 1); v += __shfl_xor(v, 2);
        v += __shfl_xor(v, 4); v += __shfl_xor(v, 8);
        lsum[r] = v;  // partial row total for this kt-half
    }
    if (col == 0) {
#pragma unroll
        for (int r = 0; r < 4; r++)
            lsum_x[qg][kh][quad * 4 + r] = lsum[r];
    }
    __syncthreads();
#pragma unroll
    for (int r = 0; r < 4; r++)
        lsum[r] = 1.0f / (lsum_x[qg][0][quad * 4 + r] + lsum_x[qg][1][quad * 4 + r]);

    // ---- pass 2: recompute S over this kt-half, write attn, accumulate P@V
    f32x4 o[6] = {};
    for (int kt = kbeg; kt < kend; kt += 64) {
#pragma unroll
        for (int nt = 0; nt < 4; nt++) {
            const unsigned short* kr = Kp + (size_t)(kt + nt * 16 + col) * DEP;
            f32x4 c = {0.f, 0.f, 0.f, 0.f};
#pragma unroll
            for (int ks = 0; ks < 3; ks++)
                c = __builtin_amdgcn_mfma_f32_16x16x32_bf16(aq[ks], ld_frag(kr + ks * 32 + quad * 8), c, 0, 0, 0);
            float mv = mask_s[kt + nt * 16 + col];
#pragma unroll
            for (int r = 0; r < 4; r++) {
                float p = __expf(c[r] * scale + mv) * lsum[r];
                attn[(size_t)(q0 + quad * 4 + r) * SEQ + kt + nt * 16 + col] = p;
                p_lds[w][(quad * 4 + r) * 72 + nt * 16 + col] = f2b(p);
            }
        }
        // P (C-layout) -> A-layout via per-wave LDS round-trip (same-wave DS ordering)
        bf16x8 pa0 = ld_frag(&p_lds[w][col * 72 + quad * 8]);
        bf16x8 pa1 = ld_frag(&p_lds[w][col * 72 + 32 + quad * 8]);
        const unsigned short* vbase = Vp + (size_t)col * SEQ + kt;
#pragma unroll
        for (int dt = 0; dt < 6; dt++) {
            const unsigned short* vr = vbase + (size_t)dt * 16 * SEQ;
            o[dt] = __builtin_amdgcn_mfma_f32_16x16x32_bf16(pa0, ld_frag(vr + quad * 8), o[dt], 0, 0, 0);
            o[dt] = __builtin_amdgcn_mfma_f32_16x16x32_bf16(pa1, ld_frag(vr + 32 + quad * 8), o[dt], 0, 0, 0);
        }
    }

    // ---- combine O partials across kt-halves (kh=1 -> kh=0), write ctx
#pragma unroll
    for (int dt = 0; dt < 6; dt++) {
        __syncthreads();
        if (kh == 1) o_xchg[qg][lane] = o[dt];
        __syncthreads();
        if (kh == 0) o[dt] += o_xchg[qg][lane];
    }
    if (kh == 0) {
#pragma unroll
        for (int dt = 0; dt < 6; dt++)
#pragma unroll
            for (int r = 0; r < 4; r++) {
                int qrow = q0 + quad * 4 + r;
                ctx[(size_t)(b * SEQ + qrow) * DM + h * DEP + dt * 16 + col] = f2b(o[dt][r]);
            }
    }
}

// ---- 5. output projection (m97 structure: global_load_lds staging, 128x128x32)
__global__ __launch_bounds__(256) void oproj_kernel(
    const unsigned short* __restrict__ ctx, const unsigned short* __restrict__ woT,
    const float* __restrict__ bo, float* __restrict__ out)
{
    __shared__ unsigned short As[128 * 32];
    __shared__ unsigned short Bs[128 * 32];

    int tid = threadIdx.x;
    int lane = tid & 63, wv_ = tid >> 6;
    int col = lane & 15, quad = lane >> 4;
    int m0 = blockIdx.x * 128, n0 = blockIdx.y * 128;
    int mi = (wv_ & 1) * 64, ni = (wv_ >> 1) * 64;
    int sr = tid >> 2, so = (tid & 3) * 8;

    f32x4 acc[4][4] = {};
    for (int kk = 0; kk < DM; kk += 32) {
        __syncthreads();
        gload_lds16(ctx + (size_t)(m0 + sr) * DM + kk + so,      &As[tid * 8]);
        gload_lds16(ctx + (size_t)(m0 + 64 + sr) * DM + kk + so, &As[2048 + tid * 8]);
        gload_lds16(woT + (size_t)(n0 + sr) * DM + kk + so,      &Bs[tid * 8]);
        gload_lds16(woT + (size_t)(n0 + 64 + sr) * DM + kk + so, &Bs[2048 + tid * 8]);
        __syncthreads();
        bf16x8 af[4], bfr[4];
#pragma unroll
        for (int mt = 0; mt < 4; mt++)
            af[mt] = ld_frag(&As[(mi + mt * 16 + col) * 32 + quad * 8]);
#pragma unroll
        for (int nt = 0; nt < 4; nt++)
            bfr[nt] = ld_frag(&Bs[(ni + nt * 16 + col) * 32 + quad * 8]);
#pragma unroll
        for (int mt = 0; mt < 4; mt++)
#pragma unroll
            for (int nt = 0; nt < 4; nt++)
                acc[mt][nt] = __builtin_amdgcn_mfma_f32_16x16x32_bf16(af[mt], bfr[nt], acc[mt][nt], 0, 0, 0);
    }
#pragma unroll
    for (int mt = 0; mt < 4; mt++) {
        int grow_base = m0 + mi + mt * 16 + quad * 4;
#pragma unroll
        for (int nt = 0; nt < 4; nt++) {
            int gcol = n0 + ni + nt * 16 + col;
            float bv_ = bo[gcol];
#pragma unroll
            for (int r = 0; r < 4; r++)
                out[(size_t)(grow_base + r) * DM + gcol] = acc[mt][nt][r] + bv_;
        }
    }
}

extern "C" void kernel_launch(void* const* d_in, const int* in_sizes, int n_in,
                              void* d_out, int out_size, void* d_ws, size_t ws_size,
                              hipStream_t stream) {
    (void)in_sizes; (void)n_in; (void)out_size; (void)ws_size;
    const float* q_in = (const float*)d_in[0];
    const float* k_in = (const float*)d_in[1];
    const float* v_in = (const float*)d_in[2];
    const float* mask = (const float*)d_in[3];
    const float* wq = (const float*)d_in[4];
    const float* bq = (const float*)d_in[5];
    const float* wk = (const float*)d_in[6];
    const float* bk = (const float*)d_in[7];
    const float* wv = (const float*)d_in[8];
    const float* bv = (const float*)d_in[9];
    const float* wo = (const float*)d_in[10];
    const float* bo = (const float*)d_in[11];

    unsigned short* ws = (unsigned short*)d_ws;
    const size_t WMAT = (size_t)DM * DM;
    const size_t QKV = (size_t)NB * NH * SEQ * DEP;  // == MROWS*DM
    unsigned short* wT    = ws;
    unsigned short* qbuf  = ws + 4 * WMAT;
    unsigned short* kbuf  = qbuf + QKV;
    unsigned short* vbuf  = kbuf + QKV;
    unsigned short* xb    = vbuf + QKV;   // 3*QKV, dead after proj_kernel
    unsigned short* vtbuf = xb;           // alias: used after proj
    unsigned short* ctxbuf = xb + QKV;    // alias: used after proj

    float* out_f = (float*)d_out;
    float* attn_f = out_f + (size_t)NB * SEQ * DM;

    dim3 blk(256);
    wt_kernel<<<dim3(24, 24, 4), blk, 0, stream>>>(wq, wk, wv, wo, wT);
    xcvt_kernel<<<dim3(3072, 1, 3), blk, 0, stream>>>(q_in, k_in, v_in, xb);
    proj_kernel<<<dim3(MROWS / 128, DM / 128, 3), blk, 0, stream>>>(
        xb, wT, bq, bk, bv, qbuf, kbuf, vbuf);
    vt_kernel<<<dim3(SEQ / 32, DEP / 32, NB * NH), blk, 0, stream>>>(vbuf, vtbuf);
    attn_kernel<<<dim3(SEQ / 32, NB * NH), blk, 0, stream>>>(
        qbuf, kbuf, vtbuf, mask, attn_f, ctxbuf);
    oproj_kernel<<<dim3(MROWS / 128, DM / 128), blk, 0, stream>>>(
        ctxbuf, wT + 3 * WMAT, bo, out_f);
}

// Round 2
// 1204.253 us; speedup vs baseline: 1.1047x; 1.1047x over previous
//
#include <hip/hip_runtime.h>
#include <hip/hip_bf16.h>
#include <stdint.h>

// ---------------------------------------------------------------------------
// MultiHeadAttention fwd. B=4 H=8 S=2048 D=768 depth=96.
// Outputs: out [4,2048,768] fp32, attn [4,8,2048,2048] fp32 (concat in d_out).
// R4:
//  - attn_kernel: keep R3's 2-way kt-split (8192 waves) but fix the R3 spill:
//    __launch_bounds__(256,6) -> VGPR cap 85 (R3's (256,8) forced 64 -> spill,
//    VGPR=32, +660MB scratch writes). 24 waves/CU.
//  - XCD swizzle: XCD r serves bh 4r..4r+3 -> K+V working set 3MB fits 4MB L2.
//  - exp2 fold: mask pre-scaled by -1e9*log2e, scale*log2e folded -> fma+exp.
// Fragment layouts: A: m=lane&15,k=quad*8+j  B(=Bt[n][k]): n=lane&15,k=quad*8+j
//                   C/D: col=lane&15, row=quad*4+reg
// ---------------------------------------------------------------------------

#define SEQ 2048
#define DM 768
#define NB 4
#define NH 8
#define DEP 96
#define MROWS 8192  // NB*SEQ

typedef __bf16 bf16x8 __attribute__((ext_vector_type(8)));
typedef float f32x4 __attribute__((ext_vector_type(4)));

__device__ inline unsigned short f2b(float f) {
    return __builtin_bit_cast(unsigned short, (__bf16)f);
}
__device__ inline bf16x8 ld_frag(const unsigned short* p) {
    return __builtin_bit_cast(bf16x8, *(const uint4*)p);
}
__device__ inline void gload_lds16(const unsigned short* g, unsigned short* l) {
    __builtin_amdgcn_global_load_lds(
        (const __attribute__((address_space(1))) unsigned int*)g,
        (__attribute__((address_space(3))) unsigned int*)l, 16, 0, 0);
}

// ---- 1. weight transpose: W fp32 [768][768] -> Wt bf16 [768][768], Wt[n][k]=W[k][n]
__global__ __launch_bounds__(256) void wt_kernel(
    const float* __restrict__ w0, const float* __restrict__ w1,
    const float* __restrict__ w2, const float* __restrict__ w3,
    unsigned short* __restrict__ wt)
{
    __shared__ float tile[32][33];
    int mat = blockIdx.z;
    const float* w = mat == 0 ? w0 : mat == 1 ? w1 : mat == 2 ? w2 : w3;
    unsigned short* dst = wt + (size_t)mat * DM * DM;
    int k0 = blockIdx.x * 32, n0 = blockIdx.y * 32;
    int tx = threadIdx.x & 31, ty = threadIdx.x >> 5;
#pragma unroll
    for (int i = 0; i < 4; i++)
        tile[ty + i * 8][tx] = w[(size_t)(k0 + ty + i * 8) * DM + n0 + tx];
    __syncthreads();
#pragma unroll
    for (int i = 0; i < 4; i++)
        dst[(size_t)(n0 + ty + i * 8) * DM + k0 + tx] = f2b(tile[tx][ty + i * 8]);
}

// ---- 1b. input convert: q_in/k_in/v_in fp32 [8192][768] -> bf16 (same layout)
__global__ __launch_bounds__(256) void xcvt_kernel(
    const float* __restrict__ q, const float* __restrict__ k, const float* __restrict__ v,
    unsigned short* __restrict__ xb)
{
    int z = blockIdx.z;
    const float* src = z == 0 ? q : z == 1 ? k : v;
    unsigned short* dst = xb + (size_t)z * MROWS * DM;
    size_t i = ((size_t)blockIdx.x * 256 + threadIdx.x) * 8;
    float4 f0 = *(const float4*)(src + i);
    float4 f1 = *(const float4*)(src + i + 4);
    bf16x8 p;
    p[0] = (__bf16)f0.x; p[1] = (__bf16)f0.y; p[2] = (__bf16)f0.z; p[3] = (__bf16)f0.w;
    p[4] = (__bf16)f1.x; p[5] = (__bf16)f1.y; p[6] = (__bf16)f1.z; p[7] = (__bf16)f1.w;
    *(uint4*)(dst + i) = __builtin_bit_cast(uint4, p);
}

// ---- 2. QKV projection GEMM (m97 structure: global_load_lds staging, 128x128x32)
__global__ __launch_bounds__(256) void proj_kernel(
    const unsigned short* __restrict__ xb, const unsigned short* __restrict__ wt,
    const float* __restrict__ bq, const float* __restrict__ bk, const float* __restrict__ bv,
    unsigned short* __restrict__ qb, unsigned short* __restrict__ kb, unsigned short* __restrict__ vb)
{
    __shared__ unsigned short As[128 * 32];
    __shared__ unsigned short Bs[128 * 32];

    int z = blockIdx.z;
    const unsigned short* x = xb + (size_t)z * MROWS * DM;
    const unsigned short* W = wt + (size_t)z * DM * DM;
    const float* bias = z == 0 ? bq : z == 1 ? bk : bv;
    unsigned short* out = z == 0 ? qb : z == 1 ? kb : vb;

    int tid = threadIdx.x;
    int lane = tid & 63, wv_ = tid >> 6;
    int col = lane & 15, quad = lane >> 4;
    int m0 = blockIdx.x * 128, n0 = blockIdx.y * 128;
    int mi = (wv_ & 1) * 64, ni = (wv_ >> 1) * 64;
    int sr = tid >> 2, so = (tid & 3) * 8;  // staging row 0..63, k-offset

    f32x4 acc[4][4] = {};
    for (int kk = 0; kk < DM; kk += 32) {
        __syncthreads();
        gload_lds16(x + (size_t)(m0 + sr) * DM + kk + so,      &As[tid * 8]);
        gload_lds16(x + (size_t)(m0 + 64 + sr) * DM + kk + so, &As[2048 + tid * 8]);
        gload_lds16(W + (size_t)(n0 + sr) * DM + kk + so,      &Bs[tid * 8]);
        gload_lds16(W + (size_t)(n0 + 64 + sr) * DM + kk + so, &Bs[2048 + tid * 8]);
        __syncthreads();
        bf16x8 af[4], bfr[4];
#pragma unroll
        for (int mt = 0; mt < 4; mt++)
            af[mt] = ld_frag(&As[(mi + mt * 16 + col) * 32 + quad * 8]);
#pragma unroll
        for (int nt = 0; nt < 4; nt++)
            bfr[nt] = ld_frag(&Bs[(ni + nt * 16 + col) * 32 + quad * 8]);
#pragma unroll
        for (int mt = 0; mt < 4; mt++)
#pragma unroll
            for (int nt = 0; nt < 4; nt++)
                acc[mt][nt] = __builtin_amdgcn_mfma_f32_16x16x32_bf16(af[mt], bfr[nt], acc[mt][nt], 0, 0, 0);
    }
#pragma unroll
    for (int mt = 0; mt < 4; mt++) {
        int grow_base = m0 + mi + mt * 16 + quad * 4;
#pragma unroll
        for (int nt = 0; nt < 4; nt++) {
            int gcol = n0 + ni + nt * 16 + col;
            float bv_ = bias[gcol];
            int h = gcol / DEP, d = gcol % DEP;
#pragma unroll
            for (int r = 0; r < 4; r++) {
                int grow = grow_base + r;
                int b = grow >> 11, s = grow & 2047;
                out[((size_t)((b * NH + h) * SEQ + s)) * DEP + d] = f2b(acc[mt][nt][r] + bv_);
            }
        }
    }
}

// ---- 3. V transpose: [bh][S][96] -> [bh][96][S] (bf16)
__global__ __launch_bounds__(256) void vt_kernel(
    const unsigned short* __restrict__ vb, unsigned short* __restrict__ vt)
{
    __shared__ unsigned short tile[32][33];
    int bh = blockIdx.z;
    int s0 = blockIdx.x * 32, d0 = blockIdx.y * 32;
    int tx = threadIdx.x & 31, ty = threadIdx.x >> 5;
    const unsigned short* src = vb + (size_t)bh * SEQ * DEP;
    unsigned short* dst = vt + (size_t)bh * DEP * SEQ;
#pragma unroll
    for (int i = 0; i < 4; i++)
        tile[ty + i * 8][tx] = src[(size_t)(s0 + ty + i * 8) * DEP + d0 + tx];
    __syncthreads();
#pragma unroll
    for (int i = 0; i < 4; i++)
        dst[(size_t)(d0 + ty + i * 8) * SEQ + s0 + tx] = tile[tx][ty + i * 8];
}

// ---- 4. attention: 2-way kt-split, 24 waves/CU, XCD-swizzled for K/V L2 locality.
// Block = 4 waves = 2 q-groups(16 rows) x 2 kt-halves. Grid 2048 blocks.
// launch_bounds(256,6): VGPR cap 85 -> no spill (R3's (256,8) spilled at 64).
__global__ __launch_bounds__(256, 6) void attn_kernel(
    const unsigned short* __restrict__ qb, const unsigned short* __restrict__ kb,
    const unsigned short* __restrict__ vt, const float* __restrict__ mask,
    float* __restrict__ attn_out, unsigned short* __restrict__ ctx)
{
    __shared__ float mask_s[SEQ];                 // 8 KB, pre-scaled by -1e9*log2e
    __shared__ unsigned short p_lds[4][16 * 72];  // per-wave P transpose, rows padded 64->72
    __shared__ float lsum_x[2][2][16];            // [qg][kh][row] partial denominators
    __shared__ f32x4 o_xchg[2][64];               // [qg][lane] O-partial exchange

    int tid = threadIdx.x;
    int w = tid >> 6, lane = tid & 63, col = lane & 15, quad = lane >> 4;
    int qg = w & 1, kh = w >> 1;

    // XCD swizzle: linear id -> XCD r (=lin%8) serves bh 4r..4r+3 only.
    // K+V working set per XCD = 4 bh * 0.75 MB = 3 MB < 4 MB L2.
    int lin = blockIdx.y * gridDim.x + blockIdx.x;   // 0..2047
    int nid = (lin & 7) * 256 + (lin >> 3);
    int bh = nid >> 6;        // 64 q-blocks per bh
    int qblk = nid & 63;
    int b = bh >> 3, h = bh & 7;
    int q0 = qblk * 32 + qg * 16;
    int kbeg = kh * (SEQ / 2), kend = kbeg + SEQ / 2;

    const unsigned short* Qp = qb + (size_t)bh * SEQ * DEP;
    const unsigned short* Kp = kb + (size_t)bh * SEQ * DEP;
    const unsigned short* Vp = vt + (size_t)bh * DEP * SEQ;
    float* attn = attn_out + (size_t)bh * SEQ * SEQ;

    const float NLOG2E = -1.4426950408889634e9f;  // -1e9 * log2(e)
    for (int i = tid; i < SEQ; i += 256)
        mask_s[i] = mask[b * SEQ + i] * NLOG2E;
    __syncthreads();

    bf16x8 aq[3];
#pragma unroll
    for (int ks = 0; ks < 3; ks++)
        aq[ks] = ld_frag(Qp + (size_t)(q0 + col) * DEP + ks * 32 + quad * 8);

    const float s2 = 0.10206207261596575f * 1.4426950408889634f;  // 1/sqrt(96)*log2e
    float lsum[4] = {0.f, 0.f, 0.f, 0.f};

    // ---- pass 1: partial denominators over this wave's kt-half
    for (int kt = kbeg; kt < kend; kt += 64) {
#pragma unroll
        for (int nt = 0; nt < 4; nt++) {
            const unsigned short* kr = Kp + (size_t)(kt + nt * 16 + col) * DEP;
            f32x4 c = {0.f, 0.f, 0.f, 0.f};
#pragma unroll
            for (int ks = 0; ks < 3; ks++)
                c = __builtin_amdgcn_mfma_f32_16x16x32_bf16(aq[ks], ld_frag(kr + ks * 32 + quad * 8), c, 0, 0, 0);
            float mv = mask_s[kt + nt * 16 + col];
#pragma unroll
            for (int r = 0; r < 4; r++)
                lsum[r] += __builtin_amdgcn_exp2f(c[r] * s2 + mv);
        }
    }
#pragma unroll
    for (int r = 0; r < 4; r++) {
        float v = lsum[r];
        v += __shfl_xor(v, 1); v += __shfl_xor(v, 2);
        v += __shfl_xor(v, 4); v += __shfl_xor(v, 8);
        lsum[r] = v;  // partial row total for this kt-half
    }
    if (col == 0) {
#pragma unroll
        for (int r = 0; r < 4; r++)
            lsum_x[qg][kh][quad * 4 + r] = lsum[r];
    }
    __syncthreads();
#pragma unroll
    for (int r = 0; r < 4; r++)
        lsum[r] = 1.0f / (lsum_x[qg][0][quad * 4 + r] + lsum_x[qg][1][quad * 4 + r]);

    // ---- pass 2: recompute S over this kt-half, write attn, accumulate P@V
    f32x4 o[6] = {};
    for (int kt = kbeg; kt < kend; kt += 64) {
#pragma unroll
        for (int nt = 0; nt < 4; nt++) {
            const unsigned short* kr = Kp + (size_t)(kt + nt * 16 + col) * DEP;
            f32x4 c = {0.f, 0.f, 0.f, 0.f};
#pragma unroll
            for (int ks = 0; ks < 3; ks++)
                c = __builtin_amdgcn_mfma_f32_16x16x32_bf16(aq[ks], ld_frag(kr + ks * 32 + quad * 8), c, 0, 0, 0);
            float mv = mask_s[kt + nt * 16 + col];
#pragma unroll
            for (int r = 0; r < 4; r++) {
                float p = __builtin_amdgcn_exp2f(c[r] * s2 + mv) * lsum[r];
                attn[(size_t)(q0 + quad * 4 + r) * SEQ + kt + nt * 16 + col] = p;
                p_lds[w][(quad * 4 + r) * 72 + nt * 16 + col] = f2b(p);
            }
        }
        // P (C-layout) -> A-layout via per-wave LDS round-trip (same-wave DS ordering)
        bf16x8 pa0 = ld_frag(&p_lds[w][col * 72 + quad * 8]);
        bf16x8 pa1 = ld_frag(&p_lds[w][col * 72 + 32 + quad * 8]);
        const unsigned short* vbase = Vp + (size_t)col * SEQ + kt;
#pragma unroll
        for (int dt = 0; dt < 6; dt++) {
            const unsigned short* vr = vbase + (size_t)dt * 16 * SEQ;
            o[dt] = __builtin_amdgcn_mfma_f32_16x16x32_bf16(pa0, ld_frag(vr + quad * 8), o[dt], 0, 0, 0);
            o[dt] = __builtin_amdgcn_mfma_f32_16x16x32_bf16(pa1, ld_frag(vr + 32 + quad * 8), o[dt], 0, 0, 0);
        }
    }

    // ---- combine O partials across kt-halves (kh=1 -> kh=0), write ctx
#pragma unroll
    for (int dt = 0; dt < 6; dt++) {
        __syncthreads();
        if (kh == 1) o_xchg[qg][lane] = o[dt];
        __syncthreads();
        if (kh == 0) o[dt] += o_xchg[qg][lane];
    }
    if (kh == 0) {
#pragma unroll
        for (int dt = 0; dt < 6; dt++)
#pragma unroll
            for (int r = 0; r < 4; r++) {
                int qrow = q0 + quad * 4 + r;
                ctx[(size_t)(b * SEQ + qrow) * DM + h * DEP + dt * 16 + col] = f2b(o[dt][r]);
            }
    }
}

// ---- 5. output projection (m97 structure: global_load_lds staging, 128x128x32)
__global__ __launch_bounds__(256) void oproj_kernel(
    const unsigned short* __restrict__ ctx, const unsigned short* __restrict__ woT,
    const float* __restrict__ bo, float* __restrict__ out)
{
    __shared__ unsigned short As[128 * 32];
    __shared__ unsigned short Bs[128 * 32];

    int tid = threadIdx.x;
    int lane = tid & 63, wv_ = tid >> 6;
    int col = lane & 15, quad = lane >> 4;
    int m0 = blockIdx.x * 128, n0 = blockIdx.y * 128;
    int mi = (wv_ & 1) * 64, ni = (wv_ >> 1) * 64;
    int sr = tid >> 2, so = (tid & 3) * 8;

    f32x4 acc[4][4] = {};
    for (int kk = 0; kk < DM; kk += 32) {
        __syncthreads();
        gload_lds16(ctx + (size_t)(m0 + sr) * DM + kk + so,      &As[tid * 8]);
        gload_lds16(ctx + (size_t)(m0 + 64 + sr) * DM + kk + so, &As[2048 + tid * 8]);
        gload_lds16(woT + (size_t)(n0 + sr) * DM + kk + so,      &Bs[tid * 8]);
        gload_lds16(woT + (size_t)(n0 + 64 + sr) * DM + kk + so, &Bs[2048 + tid * 8]);
        __syncthreads();
        bf16x8 af[4], bfr[4];
#pragma unroll
        for (int mt = 0; mt < 4; mt++)
            af[mt] = ld_frag(&As[(mi + mt * 16 + col) * 32 + quad * 8]);
#pragma unroll
        for (int nt = 0; nt < 4; nt++)
            bfr[nt] = ld_frag(&Bs[(ni + nt * 16 + col) * 32 + quad * 8]);
#pragma unroll
        for (int mt = 0; mt < 4; mt++)
#pragma unroll
            for (int nt = 0; nt < 4; nt++)
                acc[mt][nt] = __builtin_amdgcn_mfma_f32_16x16x32_bf16(af[mt], bfr[nt], acc[mt][nt], 0, 0, 0);
    }
#pragma unroll
    for (int mt = 0; mt < 4; mt++) {
        int grow_base = m0 + mi + mt * 16 + quad * 4;
#pragma unroll
        for (int nt = 0; nt < 4; nt++) {
            int gcol = n0 + ni + nt * 16 + col;
            float bv_ = bo[gcol];
#pragma unroll
            for (int r = 0; r < 4; r++)
                out[(size_t)(grow_base + r) * DM + gcol] = acc[mt][nt][r] + bv_;
        }
    }
}

extern "C" void kernel_launch(void* const* d_in, const int* in_sizes, int n_in,
                              void* d_out, int out_size, void* d_ws, size_t ws_size,
                              hipStream_t stream) {
    (void)in_sizes; (void)n_in; (void)out_size; (void)ws_size;
    const float* q_in = (const float*)d_in[0];
    const float* k_in = (const float*)d_in[1];
    const float* v_in = (const float*)d_in[2];
    const float* mask = (const float*)d_in[3];
    const float* wq = (const float*)d_in[4];
    const float* bq = (const float*)d_in[5];
    const float* wk = (const float*)d_in[6];
    const float* bk = (const float*)d_in[7];
    const float* wv = (const float*)d_in[8];
    const float* bv = (const float*)d_in[9];
    const float* wo = (const float*)d_in[10];
    const float* bo = (const float*)d_in[11];

    unsigned short* ws = (unsigned short*)d_ws;
    const size_t WMAT = (size_t)DM * DM;
    const size_t QKV = (size_t)NB * NH * SEQ * DEP;  // == MROWS*DM
    unsigned short* wT    = ws;
    unsigned short* qbuf  = ws + 4 * WMAT;
    unsigned short* kbuf  = qbuf + QKV;
    unsigned short* vbuf  = kbuf + QKV;
    unsigned short* xb    = vbuf + QKV;   // 3*QKV, dead after proj_kernel
    unsigned short* vtbuf = xb;           // alias: used after proj
    unsigned short* ctxbuf = xb + QKV;    // alias: used after proj

    float* out_f = (float*)d_out;
    float* attn_f = out_f + (size_t)NB * SEQ * DM;

    dim3 blk(256);
    wt_kernel<<<dim3(24, 24, 4), blk, 0, stream>>>(wq, wk, wv, wo, wT);
    xcvt_kernel<<<dim3(3072, 1, 3), blk, 0, stream>>>(q_in, k_in, v_in, xb);
    proj_kernel<<<dim3(MROWS / 128, DM / 128, 3), blk, 0, stream>>>(
        xb, wT, bq, bk, bv, qbuf, kbuf, vbuf);
    vt_kernel<<<dim3(SEQ / 32, DEP / 32, NB * NH), blk, 0, stream>>>(vbuf, vtbuf);
    attn_kernel<<<dim3(SEQ / 32, NB * NH), blk, 0, stream>>>(
        qbuf, kbuf, vtbuf, mask, attn_f, ctxbuf);
    oproj_kernel<<<dim3(MROWS / 128, DM / 128), blk, 0, stream>>>(
        ctxbuf, wT + 3 * WMAT, bo, out_f);
}

// Round 3
// 1041.458 us; speedup vs baseline: 1.2774x; 1.1563x over previous
//
#include <hip/hip_runtime.h>
#include <hip/hip_bf16.h>
#include <stdint.h>

// ---------------------------------------------------------------------------
// MultiHeadAttention fwd. B=4 H=8 S=2048 D=768 depth=96.
// Outputs: out [4,2048,768] fp32, attn [4,8,2048,2048] fp32 (concat in d_out).
// R5:
//  - attn_kernel: launch_bounds back to (256,4) (R2-proven 56 VGPR, no spill).
//    Min-waves hints (256,8)/(256,6) caused the allocator to spill at HALF the
//    cap (VGPR 32/40, +115-660MB scratch). 56 VGPR + 19.5KB LDS already allows
//    8 blocks/CU; the 2048-block grid (kt-split) is what exposes them.
//  - proj/oproj: T3 minimum 2-phase — double-buffered LDS (32KB, 5 blocks/CU),
//    stage tile t+1 before computing tile t, one barrier per iter. Kills the
//    per-iter vmcnt(0) full drain (24 iters x ~450cy exposed latency).
// Fragment layouts: A: m=lane&15,k=quad*8+j  B(=Bt[n][k]): n=lane&15,k=quad*8+j
//                   C/D: col=lane&15, row=quad*4+reg
// ---------------------------------------------------------------------------

#define SEQ 2048
#define DM 768
#define NB 4
#define NH 8
#define DEP 96
#define MROWS 8192  // NB*SEQ

typedef __bf16 bf16x8 __attribute__((ext_vector_type(8)));
typedef float f32x4 __attribute__((ext_vector_type(4)));

__device__ inline unsigned short f2b(float f) {
    return __builtin_bit_cast(unsigned short, (__bf16)f);
}
__device__ inline bf16x8 ld_frag(const unsigned short* p) {
    return __builtin_bit_cast(bf16x8, *(const uint4*)p);
}
__device__ inline void gload_lds16(const unsigned short* g, unsigned short* l) {
    __builtin_amdgcn_global_load_lds(
        (const __attribute__((address_space(1))) unsigned int*)g,
        (__attribute__((address_space(3))) unsigned int*)l, 16, 0, 0);
}

// ---- 1. weight transpose: W fp32 [768][768] -> Wt bf16 [768][768], Wt[n][k]=W[k][n]
__global__ __launch_bounds__(256) void wt_kernel(
    const float* __restrict__ w0, const float* __restrict__ w1,
    const float* __restrict__ w2, const float* __restrict__ w3,
    unsigned short* __restrict__ wt)
{
    __shared__ float tile[32][33];
    int mat = blockIdx.z;
    const float* w = mat == 0 ? w0 : mat == 1 ? w1 : mat == 2 ? w2 : w3;
    unsigned short* dst = wt + (size_t)mat * DM * DM;
    int k0 = blockIdx.x * 32, n0 = blockIdx.y * 32;
    int tx = threadIdx.x & 31, ty = threadIdx.x >> 5;
#pragma unroll
    for (int i = 0; i < 4; i++)
        tile[ty + i * 8][tx] = w[(size_t)(k0 + ty + i * 8) * DM + n0 + tx];
    __syncthreads();
#pragma unroll
    for (int i = 0; i < 4; i++)
        dst[(size_t)(n0 + ty + i * 8) * DM + k0 + tx] = f2b(tile[tx][ty + i * 8]);
}

// ---- 1b. input convert: q_in/k_in/v_in fp32 [8192][768] -> bf16 (same layout)
__global__ __launch_bounds__(256) void xcvt_kernel(
    const float* __restrict__ q, const float* __restrict__ k, const float* __restrict__ v,
    unsigned short* __restrict__ xb)
{
    int z = blockIdx.z;
    const float* src = z == 0 ? q : z == 1 ? k : v;
    unsigned short* dst = xb + (size_t)z * MROWS * DM;
    size_t i = ((size_t)blockIdx.x * 256 + threadIdx.x) * 8;
    float4 f0 = *(const float4*)(src + i);
    float4 f1 = *(const float4*)(src + i + 4);
    bf16x8 p;
    p[0] = (__bf16)f0.x; p[1] = (__bf16)f0.y; p[2] = (__bf16)f0.z; p[3] = (__bf16)f0.w;
    p[4] = (__bf16)f1.x; p[5] = (__bf16)f1.y; p[6] = (__bf16)f1.z; p[7] = (__bf16)f1.w;
    *(uint4*)(dst + i) = __builtin_bit_cast(uint4, p);
}

// ---- 2. QKV projection GEMM: 2-phase double-buffered global_load_lds staging
__global__ __launch_bounds__(256) void proj_kernel(
    const unsigned short* __restrict__ xb, const unsigned short* __restrict__ wt,
    const float* __restrict__ bq, const float* __restrict__ bk, const float* __restrict__ bv,
    unsigned short* __restrict__ qb, unsigned short* __restrict__ kb, unsigned short* __restrict__ vb)
{
    __shared__ unsigned short As[2][128 * 32];
    __shared__ unsigned short Bs[2][128 * 32];

    int z = blockIdx.z;
    const unsigned short* x = xb + (size_t)z * MROWS * DM;
    const unsigned short* W = wt + (size_t)z * DM * DM;
    const float* bias = z == 0 ? bq : z == 1 ? bk : bv;
    unsigned short* out = z == 0 ? qb : z == 1 ? kb : vb;

    int tid = threadIdx.x;
    int lane = tid & 63, wv_ = tid >> 6;
    int col = lane & 15, quad = lane >> 4;
    int m0 = blockIdx.x * 128, n0 = blockIdx.y * 128;
    int mi = (wv_ & 1) * 64, ni = (wv_ >> 1) * 64;
    int sr = tid >> 2, so = (tid & 3) * 8;  // staging row 0..63, k-offset

    const unsigned short* xs0 = x + (size_t)(m0 + sr) * DM + so;
    const unsigned short* xs1 = x + (size_t)(m0 + 64 + sr) * DM + so;
    const unsigned short* ws0 = W + (size_t)(n0 + sr) * DM + so;
    const unsigned short* ws1 = W + (size_t)(n0 + 64 + sr) * DM + so;

    f32x4 acc[4][4] = {};
    // prologue: stage tile 0 into buffer 0
    gload_lds16(xs0, &As[0][tid * 8]);
    gload_lds16(xs1, &As[0][2048 + tid * 8]);
    gload_lds16(ws0, &Bs[0][tid * 8]);
    gload_lds16(ws1, &Bs[0][2048 + tid * 8]);
    __syncthreads();

    for (int t = 0; t < DM / 32; ++t) {
        int cur = t & 1;
        if (t < DM / 32 - 1) {  // stage next tile into other buffer
            int kk = (t + 1) * 32;
            gload_lds16(xs0 + kk, &As[cur ^ 1][tid * 8]);
            gload_lds16(xs1 + kk, &As[cur ^ 1][2048 + tid * 8]);
            gload_lds16(ws0 + kk, &Bs[cur ^ 1][tid * 8]);
            gload_lds16(ws1 + kk, &Bs[cur ^ 1][2048 + tid * 8]);
        }
        bf16x8 af[4], bfr[4];
#pragma unroll
        for (int mt = 0; mt < 4; mt++)
            af[mt] = ld_frag(&As[cur][(mi + mt * 16 + col) * 32 + quad * 8]);
#pragma unroll
        for (int nt = 0; nt < 4; nt++)
            bfr[nt] = ld_frag(&Bs[cur][(ni + nt * 16 + col) * 32 + quad * 8]);
#pragma unroll
        for (int mt = 0; mt < 4; mt++)
#pragma unroll
            for (int nt = 0; nt < 4; nt++)
                acc[mt][nt] = __builtin_amdgcn_mfma_f32_16x16x32_bf16(af[mt], bfr[nt], acc[mt][nt], 0, 0, 0);
        __syncthreads();  // drains next-tile loads; guards cur-buffer reuse
    }
#pragma unroll
    for (int mt = 0; mt < 4; mt++) {
        int grow_base = m0 + mi + mt * 16 + quad * 4;
#pragma unroll
        for (int nt = 0; nt < 4; nt++) {
            int gcol = n0 + ni + nt * 16 + col;
            float bv_ = bias[gcol];
            int h = gcol / DEP, d = gcol % DEP;
#pragma unroll
            for (int r = 0; r < 4; r++) {
                int grow = grow_base + r;
                int b = grow >> 11, s = grow & 2047;
                out[((size_t)((b * NH + h) * SEQ + s)) * DEP + d] = f2b(acc[mt][nt][r] + bv_);
            }
        }
    }
}

// ---- 3. V transpose: [bh][S][96] -> [bh][96][S] (bf16)
__global__ __launch_bounds__(256) void vt_kernel(
    const unsigned short* __restrict__ vb, unsigned short* __restrict__ vt)
{
    __shared__ unsigned short tile[32][33];
    int bh = blockIdx.z;
    int s0 = blockIdx.x * 32, d0 = blockIdx.y * 32;
    int tx = threadIdx.x & 31, ty = threadIdx.x >> 5;
    const unsigned short* src = vb + (size_t)bh * SEQ * DEP;
    unsigned short* dst = vt + (size_t)bh * DEP * SEQ;
#pragma unroll
    for (int i = 0; i < 4; i++)
        tile[ty + i * 8][tx] = src[(size_t)(s0 + ty + i * 8) * DEP + d0 + tx];
    __syncthreads();
#pragma unroll
    for (int i = 0; i < 4; i++)
        dst[(size_t)(d0 + ty + i * 8) * SEQ + s0 + tx] = tile[tx][ty + i * 8];
}

// ---- 4. attention: 2-way kt-split, XCD-swizzled, (256,4) = no spill.
// Block = 4 waves = 2 q-groups(16 rows) x 2 kt-halves. Grid 2048 blocks.
// VGPR ~56 + LDS 19.5KB -> hardware reaches 8 blocks/CU (32 waves) naturally.
__global__ __launch_bounds__(256, 4) void attn_kernel(
    const unsigned short* __restrict__ qb, const unsigned short* __restrict__ kb,
    const unsigned short* __restrict__ vt, const float* __restrict__ mask,
    float* __restrict__ attn_out, unsigned short* __restrict__ ctx)
{
    __shared__ float mask_s[SEQ];                 // 8 KB, pre-scaled by -1e9*log2e
    __shared__ unsigned short p_lds[4][16 * 72];  // per-wave P transpose, rows padded 64->72
    __shared__ float lsum_x[2][2][16];            // [qg][kh][row] partial denominators
    __shared__ f32x4 o_xchg[2][64];               // [qg][lane] O-partial exchange

    int tid = threadIdx.x;
    int w = tid >> 6, lane = tid & 63, col = lane & 15, quad = lane >> 4;
    int qg = w & 1, kh = w >> 1;

    // XCD swizzle: linear id -> XCD r (=lin%8) serves bh 4r..4r+3 only.
    // K+V working set per XCD = 4 bh * 0.75 MB = 3 MB < 4 MB L2.
    int lin = blockIdx.y * gridDim.x + blockIdx.x;   // 0..2047
    int nid = (lin & 7) * 256 + (lin >> 3);
    int bh = nid >> 6;        // 64 q-blocks per bh
    int qblk = nid & 63;
    int b = bh >> 3, h = bh & 7;
    int q0 = qblk * 32 + qg * 16;
    int kbeg = kh * (SEQ / 2), kend = kbeg + SEQ / 2;

    const unsigned short* Qp = qb + (size_t)bh * SEQ * DEP;
    const unsigned short* Kp = kb + (size_t)bh * SEQ * DEP;
    const unsigned short* Vp = vt + (size_t)bh * DEP * SEQ;
    float* attn = attn_out + (size_t)bh * SEQ * SEQ;

    const float NLOG2E = -1.4426950408889634e9f;  // -1e9 * log2(e)
    for (int i = tid; i < SEQ; i += 256)
        mask_s[i] = mask[b * SEQ + i] * NLOG2E;
    __syncthreads();

    bf16x8 aq[3];
#pragma unroll
    for (int ks = 0; ks < 3; ks++)
        aq[ks] = ld_frag(Qp + (size_t)(q0 + col) * DEP + ks * 32 + quad * 8);

    const float s2 = 0.10206207261596575f * 1.4426950408889634f;  // 1/sqrt(96)*log2e
    float lsum[4] = {0.f, 0.f, 0.f, 0.f};

    // ---- pass 1: partial denominators over this wave's kt-half
    for (int kt = kbeg; kt < kend; kt += 64) {
#pragma unroll
        for (int nt = 0; nt < 4; nt++) {
            const unsigned short* kr = Kp + (size_t)(kt + nt * 16 + col) * DEP;
            f32x4 c = {0.f, 0.f, 0.f, 0.f};
#pragma unroll
            for (int ks = 0; ks < 3; ks++)
                c = __builtin_amdgcn_mfma_f32_16x16x32_bf16(aq[ks], ld_frag(kr + ks * 32 + quad * 8), c, 0, 0, 0);
            float mv = mask_s[kt + nt * 16 + col];
#pragma unroll
            for (int r = 0; r < 4; r++)
                lsum[r] += __builtin_amdgcn_exp2f(c[r] * s2 + mv);
        }
    }
#pragma unroll
    for (int r = 0; r < 4; r++) {
        float v = lsum[r];
        v += __shfl_xor(v, 1); v += __shfl_xor(v, 2);
        v += __shfl_xor(v, 4); v += __shfl_xor(v, 8);
        lsum[r] = v;  // partial row total for this kt-half
    }
    if (col == 0) {
#pragma unroll
        for (int r = 0; r < 4; r++)
            lsum_x[qg][kh][quad * 4 + r] = lsum[r];
    }
    __syncthreads();
#pragma unroll
    for (int r = 0; r < 4; r++)
        lsum[r] = 1.0f / (lsum_x[qg][0][quad * 4 + r] + lsum_x[qg][1][quad * 4 + r]);

    // ---- pass 2: recompute S over this kt-half, write attn, accumulate P@V
    f32x4 o[6] = {};
    for (int kt = kbeg; kt < kend; kt += 64) {
#pragma unroll
        for (int nt = 0; nt < 4; nt++) {
            const unsigned short* kr = Kp + (size_t)(kt + nt * 16 + col) * DEP;
            f32x4 c = {0.f, 0.f, 0.f, 0.f};
#pragma unroll
            for (int ks = 0; ks < 3; ks++)
                c = __builtin_amdgcn_mfma_f32_16x16x32_bf16(aq[ks], ld_frag(kr + ks * 32 + quad * 8), c, 0, 0, 0);
            float mv = mask_s[kt + nt * 16 + col];
#pragma unroll
            for (int r = 0; r < 4; r++) {
                float p = __builtin_amdgcn_exp2f(c[r] * s2 + mv) * lsum[r];
                attn[(size_t)(q0 + quad * 4 + r) * SEQ + kt + nt * 16 + col] = p;
                p_lds[w][(quad * 4 + r) * 72 + nt * 16 + col] = f2b(p);
            }
        }
        // P (C-layout) -> A-layout via per-wave LDS round-trip (same-wave DS ordering)
        bf16x8 pa0 = ld_frag(&p_lds[w][col * 72 + quad * 8]);
        bf16x8 pa1 = ld_frag(&p_lds[w][col * 72 + 32 + quad * 8]);
        const unsigned short* vbase = Vp + (size_t)col * SEQ + kt;
#pragma unroll
        for (int dt = 0; dt < 6; dt++) {
            const unsigned short* vr = vbase + (size_t)dt * 16 * SEQ;
            o[dt] = __builtin_amdgcn_mfma_f32_16x16x32_bf16(pa0, ld_frag(vr + quad * 8), o[dt], 0, 0, 0);
            o[dt] = __builtin_amdgcn_mfma_f32_16x16x32_bf16(pa1, ld_frag(vr + 32 + quad * 8), o[dt], 0, 0, 0);
        }
    }

    // ---- combine O partials across kt-halves (kh=1 -> kh=0), write ctx
#pragma unroll
    for (int dt = 0; dt < 6; dt++) {
        __syncthreads();
        if (kh == 1) o_xchg[qg][lane] = o[dt];
        __syncthreads();
        if (kh == 0) o[dt] += o_xchg[qg][lane];
    }
    if (kh == 0) {
#pragma unroll
        for (int dt = 0; dt < 6; dt++)
#pragma unroll
            for (int r = 0; r < 4; r++) {
                int qrow = q0 + quad * 4 + r;
                ctx[(size_t)(b * SEQ + qrow) * DM + h * DEP + dt * 16 + col] = f2b(o[dt][r]);
            }
    }
}

// ---- 5. output projection: 2-phase double-buffered global_load_lds staging
__global__ __launch_bounds__(256) void oproj_kernel(
    const unsigned short* __restrict__ ctx, const unsigned short* __restrict__ woT,
    const float* __restrict__ bo, float* __restrict__ out)
{
    __shared__ unsigned short As[2][128 * 32];
    __shared__ unsigned short Bs[2][128 * 32];

    int tid = threadIdx.x;
    int lane = tid & 63, wv_ = tid >> 6;
    int col = lane & 15, quad = lane >> 4;
    int m0 = blockIdx.x * 128, n0 = blockIdx.y * 128;
    int mi = (wv_ & 1) * 64, ni = (wv_ >> 1) * 64;
    int sr = tid >> 2, so = (tid & 3) * 8;

    const unsigned short* xs0 = ctx + (size_t)(m0 + sr) * DM + so;
    const unsigned short* xs1 = ctx + (size_t)(m0 + 64 + sr) * DM + so;
    const unsigned short* ws0 = woT + (size_t)(n0 + sr) * DM + so;
    const unsigned short* ws1 = woT + (size_t)(n0 + 64 + sr) * DM + so;

    f32x4 acc[4][4] = {};
    gload_lds16(xs0, &As[0][tid * 8]);
    gload_lds16(xs1, &As[0][2048 + tid * 8]);
    gload_lds16(ws0, &Bs[0][tid * 8]);
    gload_lds16(ws1, &Bs[0][2048 + tid * 8]);
    __syncthreads();

    for (int t = 0; t < DM / 32; ++t) {
        int cur = t & 1;
        if (t < DM / 32 - 1) {
            int kk = (t + 1) * 32;
            gload_lds16(xs0 + kk, &As[cur ^ 1][tid * 8]);
            gload_lds16(xs1 + kk, &As[cur ^ 1][2048 + tid * 8]);
            gload_lds16(ws0 + kk, &Bs[cur ^ 1][tid * 8]);
            gload_lds16(ws1 + kk, &Bs[cur ^ 1][2048 + tid * 8]);
        }
        bf16x8 af[4], bfr[4];
#pragma unroll
        for (int mt = 0; mt < 4; mt++)
            af[mt] = ld_frag(&As[cur][(mi + mt * 16 + col) * 32 + quad * 8]);
#pragma unroll
        for (int nt = 0; nt < 4; nt++)
            bfr[nt] = ld_frag(&Bs[cur][(ni + nt * 16 + col) * 32 + quad * 8]);
#pragma unroll
        for (int mt = 0; mt < 4; mt++)
#pragma unroll
            for (int nt = 0; nt < 4; nt++)
                acc[mt][nt] = __builtin_amdgcn_mfma_f32_16x16x32_bf16(af[mt], bfr[nt], acc[mt][nt], 0, 0, 0);
        __syncthreads();
    }
#pragma unroll
    for (int mt = 0; mt < 4; mt++) {
        int grow_base = m0 + mi + mt * 16 + quad * 4;
#pragma unroll
        for (int nt = 0; nt < 4; nt++) {
            int gcol = n0 + ni + nt * 16 + col;
            float bv_ = bo[gcol];
#pragma unroll
            for (int r = 0; r < 4; r++)
                out[(size_t)(grow_base + r) * DM + gcol] = acc[mt][nt][r] + bv_;
        }
    }
}

extern "C" void kernel_launch(void* const* d_in, const int* in_sizes, int n_in,
                              void* d_out, int out_size, void* d_ws, size_t ws_size,
                              hipStream_t stream) {
    (void)in_sizes; (void)n_in; (void)out_size; (void)ws_size;
    const float* q_in = (const float*)d_in[0];
    const float* k_in = (const float*)d_in[1];
    const float* v_in = (const float*)d_in[2];
    const float* mask = (const float*)d_in[3];
    const float* wq = (const float*)d_in[4];
    const float* bq = (const float*)d_in[5];
    const float* wk = (const float*)d_in[6];
    const float* bk = (const float*)d_in[7];
    const float* wv = (const float*)d_in[8];
    const float* bv = (const float*)d_in[9];
    const float* wo = (const float*)d_in[10];
    const float* bo = (const float*)d_in[11];

    unsigned short* ws = (unsigned short*)d_ws;
    const size_t WMAT = (size_t)DM * DM;
    const size_t QKV = (size_t)NB * NH * SEQ * DEP;  // == MROWS*DM
    unsigned short* wT    = ws;
    unsigned short* qbuf  = ws + 4 * WMAT;
    unsigned short* kbuf  = qbuf + QKV;
    unsigned short* vbuf  = kbuf + QKV;
    unsigned short* xb    = vbuf + QKV;   // 3*QKV, dead after proj_kernel
    unsigned short* vtbuf = xb;           // alias: used after proj
    unsigned short* ctxbuf = xb + QKV;    // alias: used after proj

    float* out_f = (float*)d_out;
    float* attn_f = out_f + (size_t)NB * SEQ * DM;

    dim3 blk(256);
    wt_kernel<<<dim3(24, 24, 4), blk, 0, stream>>>(wq, wk, wv, wo, wT);
    xcvt_kernel<<<dim3(3072, 1, 3), blk, 0, stream>>>(q_in, k_in, v_in, xb);
    proj_kernel<<<dim3(MROWS / 128, DM / 128, 3), blk, 0, stream>>>(
        xb, wT, bq, bk, bv, qbuf, kbuf, vbuf);
    vt_kernel<<<dim3(SEQ / 32, DEP / 32, NB * NH), blk, 0, stream>>>(vbuf, vtbuf);
    attn_kernel<<<dim3(SEQ / 32, NB * NH), blk, 0, stream>>>(
        qbuf, kbuf, vtbuf, mask, attn_f, ctxbuf);
    oproj_kernel<<<dim3(MROWS / 128, DM / 128), blk, 0, stream>>>(
        ctxbuf, wT + 3 * WMAT, bo, out_f);
}